// Round 1
// baseline (480.283 us; speedup 1.0000x reference)
//
#include <hip/hip_runtime.h>
#include <hip/hip_bf16.h>
#include <cstdint>

#define BATCH 4
#define CDIM 256
#define NTOK 4096
#define IDIM 128

typedef __attribute__((ext_vector_type(4))) float f32x4;
typedef __attribute__((ext_vector_type(8))) short short8;

// round-to-nearest-even fp32 -> bf16 (values are finite here; no NaN path needed)
static __device__ __forceinline__ unsigned bf16_rn(float f) {
  union { float f; unsigned u; } v; v.f = f;
  return (v.u + 0x7fffu + ((v.u >> 16) & 1u)) >> 16;
}
static __device__ __forceinline__ unsigned pack_bf16(float a, float b) {
  return bf16_rn(a) | (bf16_rn(b) << 16);
}

// ---------------------------------------------------------------------------
// Phase 1: QKV projection.
//   Q[b][n][i]  = sum_c w_theta[i][c] * x[b][c][n]   (bf16, row-major in i)
//   K[b][m][i]  = sum_c w_phi[i][c]   * x[b][c][m]   (bf16, row-major in i)
//   Vt[b][i][n] = sum_c w_g[i][c]     * x[b][c][n]   (bf16, row-major in n)
// Block: 256 thr, tile = 64 tokens x all 384 rows. x tile staged in LDS.
// ---------------------------------------------------------------------------
__global__ __launch_bounds__(256) void qkv_kernel(
    const float* __restrict__ x, const float* __restrict__ wt,
    const float* __restrict__ wp, const float* __restrict__ wg,
    unsigned short* __restrict__ Q, unsigned short* __restrict__ K,
    unsigned short* __restrict__ Vt)
{
  __shared__ float xs[CDIM][64];
  const int b = blockIdx.y;
  const int n0 = blockIdx.x * 64;
  const int t = threadIdx.x;
  const float* xb = x + (size_t)b * CDIM * NTOK;
#pragma unroll
  for (int it = 0; it < 16; ++it) {
    int f4 = it * 256 + t;
    int c = f4 >> 4, n4 = (f4 & 15) * 4;
    *(float4*)&xs[c][n4] = *(const float4*)&xb[(size_t)c * NTOK + n0 + n4];
  }
  __syncthreads();
  const int lane = t & 63;
  // wave id, forced wave-uniform so weight loads become scalar loads
  const int wvu = __builtin_amdgcn_readfirstlane(t >> 6);

  for (int ch = 0; ch < 6; ++ch) {
    const int I0 = wvu * 96 + ch * 16;  // 16 projection rows per chunk, never straddles 128-boundaries
    const float* wbase;
    int sel;
    if (I0 < 128)      { wbase = wt + (size_t)I0 * CDIM;        sel = 0; }
    else if (I0 < 256) { wbase = wp + (size_t)(I0 - 128) * CDIM; sel = 1; }
    else               { wbase = wg + (size_t)(I0 - 256) * CDIM; sel = 2; }

    float acc[16];
#pragma unroll
    for (int j = 0; j < 16; ++j) acc[j] = 0.f;

    for (int c4 = 0; c4 < CDIM; c4 += 4) {
      float4 wr[16];
#pragma unroll
      for (int j = 0; j < 16; ++j)
        wr[j] = *(const float4*)&wbase[(size_t)j * CDIM + c4];
#pragma unroll
      for (int cc = 0; cc < 4; ++cc) {
        float xv = xs[c4 + cc][lane];
#pragma unroll
        for (int j = 0; j < 16; ++j)
          acc[j] = fmaf(((const float*)&wr[j])[cc], xv, acc[j]);
      }
    }

    if (sel == 2) {
      // Vt[b][i][n]: lane==n varies fastest -> each store is 128B coalesced
      unsigned short* dst = Vt + ((size_t)b * IDIM + (I0 - 256)) * NTOK + n0 + lane;
#pragma unroll
      for (int j = 0; j < 16; ++j)
        dst[(size_t)j * NTOK] = (unsigned short)bf16_rn(acc[j]);
    } else {
      // Q/K[b][n][i]: 16 consecutive i at fixed n -> two 16B stores per lane
      unsigned short tmp[16];
#pragma unroll
      for (int j = 0; j < 16; ++j) tmp[j] = (unsigned short)bf16_rn(acc[j]);
      unsigned short* dst = (sel == 0 ? Q : K) +
          ((size_t)b * NTOK + n0 + lane) * IDIM + (I0 & 127);
      *(short8*)dst       = *(short8*)&tmp[0];
      *(short8*)(dst + 8) = *(short8*)&tmp[8];
    }
  }
}

// ---------------------------------------------------------------------------
// Phase 2: flash attention (no scale), swapped-operand form.
//   St[m][n] = sum_i K[m][i] * Q[n][i]   (softmax over m = St rows)
//   Ot[i][n] = sum_m Vt[i][m] * P^T[m][n] / L[n]
// Block: 4 waves x 16 n-columns; loop m in steps of 32. All operands loaded
// directly from global (L2-resident; XCD swizzle keeps each b on one XCD pair).
// Per-wave, barrier-free.
// ---------------------------------------------------------------------------
__global__ __launch_bounds__(256) void attn_kernel(
    const unsigned short* __restrict__ Q, const unsigned short* __restrict__ K,
    const unsigned short* __restrict__ Vt, float* __restrict__ Ot)
{
  const int bid = blockIdx.x;
  const int xcd = bid & 7;              // HW round-robins blocks across 8 XCDs
  const int b = xcd >> 1;               // batch pinned to an XCD pair
  const int ntile = (xcd & 1) * 32 + (bid >> 3);
  const int t = threadIdx.x;
  const int lane = t & 63;
  const int wv = t >> 6;
  const int n0 = ntile * 64 + wv * 16;
  const int g = lane >> 4, cl = lane & 15;

  // Q fragments (B operand): B[k=i][col=n] = Q[n][i], 16B/lane contiguous
  const unsigned short* Qb = Q + ((size_t)b * NTOK + n0 + cl) * IDIM + g * 8;
  short8 q[4];
#pragma unroll
  for (int kc = 0; kc < 4; ++kc) q[kc] = *(const short8*)(Qb + kc * 32);

  const unsigned short* Kb = K + (size_t)b * NTOK * IDIM;
  const unsigned short* Vb = Vt + (size_t)b * IDIM * NTOK;

  f32x4 o[8];
#pragma unroll
  for (int i = 0; i < 8; ++i) o[i] = (f32x4){0.f, 0.f, 0.f, 0.f};
  float M = -3.0e38f, L = 0.f;

  const int l0 = ((g * 32 + cl) & 63) * 4;        // bpermute byte indices
  const int l1 = ((g * 32 + 16 + cl) & 63) * 4;
  const bool lowg = (g < 2);

  for (int m0 = 0; m0 < NTOK; m0 += 32) {
    // ---- St = K . Q^T : two 16-row m-tiles --------------------------------
    const unsigned short* kp = Kb + (size_t)(m0 + cl) * IDIM + g * 8;
    f32x4 s0 = {0.f, 0.f, 0.f, 0.f}, s1 = {0.f, 0.f, 0.f, 0.f};
#pragma unroll
    for (int kc = 0; kc < 4; ++kc) {
      short8 ka = *(const short8*)(kp + kc * 32);
      s0 = __builtin_amdgcn_mfma_f32_16x16x32_bf16(ka, q[kc], s0, 0, 0, 0);
    }
#pragma unroll
    for (int kc = 0; kc < 4; ++kc) {
      short8 ka = *(const short8*)(kp + 16 * IDIM + kc * 32);
      s1 = __builtin_amdgcn_mfma_f32_16x16x32_bf16(ka, q[kc], s1, 0, 0, 0);
    }
    // lane holds St[m][n]: n = n0+cl, m in {m0+4g+r, m0+16+4g+r}

    // ---- online softmax over m (column stats; lanes cl,cl+16,cl+32,cl+48) -
    float sm = fmaxf(fmaxf(fmaxf(s0[0], s0[1]), fmaxf(s0[2], s0[3])),
                     fmaxf(fmaxf(s1[0], s1[1]), fmaxf(s1[2], s1[3])));
    sm = fmaxf(sm, __shfl_xor(sm, 16));
    sm = fmaxf(sm, __shfl_xor(sm, 32));
    float Mn = fmaxf(M, sm);
    float scale = __expf(M - Mn);
    M = Mn;
    float p0[4], p1[4];
#pragma unroll
    for (int r = 0; r < 4; ++r) {
      p0[r] = __expf(s0[r] - Mn);
      p1[r] = __expf(s1[r] - Mn);
    }
    float ls = (p0[0] + p0[1] + p0[2] + p0[3]) + (p1[0] + p1[1] + p1[2] + p1[3]);
    ls += __shfl_xor(ls, 16);
    ls += __shfl_xor(ls, 32);
    L = L * scale + ls;
#pragma unroll
    for (int i = 0; i < 8; ++i) o[i] *= scale;

    // ---- P^T -> bf16 B-fragment via in-register pack + ds_bpermute --------
    // dest lane (g,n) word w needs P^T[m=8g+2w,8g+2w+1][n]; source lane holds
    // packed pairs A*(m<16)/B*(m>=16) at lanes (32g+n)&63 and (32g+16+n)&63.
    unsigned A0 = pack_bf16(p0[0], p0[1]), A1 = pack_bf16(p0[2], p0[3]);
    unsigned B0 = pack_bf16(p1[0], p1[1]), B1 = pack_bf16(p1[2], p1[3]);
    int w0a = __builtin_amdgcn_ds_bpermute(l0, (int)A0);
    int w0b = __builtin_amdgcn_ds_bpermute(l0, (int)B0);
    int w1a = __builtin_amdgcn_ds_bpermute(l0, (int)A1);
    int w1b = __builtin_amdgcn_ds_bpermute(l0, (int)B1);
    int w2a = __builtin_amdgcn_ds_bpermute(l1, (int)A0);
    int w2b = __builtin_amdgcn_ds_bpermute(l1, (int)B0);
    int w3a = __builtin_amdgcn_ds_bpermute(l1, (int)A1);
    int w3b = __builtin_amdgcn_ds_bpermute(l1, (int)B1);
    union { int u[4]; short8 s; } pf;
    pf.u[0] = lowg ? w0a : w0b;
    pf.u[1] = lowg ? w1a : w1b;
    pf.u[2] = lowg ? w2a : w2b;
    pf.u[3] = lowg ? w3a : w3b;

    // ---- Ot += Vt . P^T ---------------------------------------------------
    const unsigned short* vp = Vb + (size_t)cl * NTOK + m0 + g * 8;
#pragma unroll
    for (int i = 0; i < 8; ++i) {
      short8 va = *(const short8*)(vp + (size_t)(i * 16) * NTOK);
      o[i] = __builtin_amdgcn_mfma_f32_16x16x32_bf16(va, pf.s, o[i], 0, 0, 0);
    }
  }

  const float rinv = 1.0f / L;
  float* op = Ot + (size_t)b * IDIM * NTOK + n0 + cl;
#pragma unroll
  for (int i = 0; i < 8; ++i)
#pragma unroll
    for (int r = 0; r < 4; ++r)
      op[(size_t)(i * 16 + g * 4 + r) * NTOK] = o[i][r] * rinv;
}

// ---------------------------------------------------------------------------
// Phase 3: out[b][c][n] = x[b][c][n] + sum_i w_out[c][i] * Ot[b][i][n]
// Block: 256 thr, tile = 64 tokens x all 256 channels; Ot tile in LDS.
// ---------------------------------------------------------------------------
__global__ __launch_bounds__(256) void out_kernel(
    const float* __restrict__ x, const float* __restrict__ wo,
    const float* __restrict__ Ot, float* __restrict__ out)
{
  __shared__ float os[IDIM][68];  // pad 68: 16B-aligned rows, conflict-free n-reads
  const int b = blockIdx.y, n0 = blockIdx.x * 64;
  const int t = threadIdx.x;
  const float* Ob = Ot + (size_t)b * IDIM * NTOK;
#pragma unroll
  for (int it = 0; it < 8; ++it) {
    int f4 = it * 256 + t;
    int i = f4 >> 4, n4 = (f4 & 15) * 4;
    *(float4*)&os[i][n4] = *(const float4*)&Ob[(size_t)i * NTOK + n0 + n4];
  }
  __syncthreads();
  const int lane = t & 63;
  const int wvu = __builtin_amdgcn_readfirstlane(t >> 6);
  const float* xb = x + (size_t)b * CDIM * NTOK + n0 + lane;
  float* ob = out + (size_t)b * CDIM * NTOK + n0 + lane;

  for (int cb = 0; cb < 64; cb += 4) {
    const int c = wvu * 64 + cb;
    float a0 = xb[(size_t)(c + 0) * NTOK];
    float a1 = xb[(size_t)(c + 1) * NTOK];
    float a2 = xb[(size_t)(c + 2) * NTOK];
    float a3 = xb[(size_t)(c + 3) * NTOK];
    const float* w0 = wo + (size_t)(c + 0) * IDIM;
    const float* w1 = wo + (size_t)(c + 1) * IDIM;
    const float* w2 = wo + (size_t)(c + 2) * IDIM;
    const float* w3 = wo + (size_t)(c + 3) * IDIM;
    for (int i = 0; i < IDIM; ++i) {
      float ov = os[i][lane];
      a0 = fmaf(w0[i], ov, a0);
      a1 = fmaf(w1[i], ov, a1);
      a2 = fmaf(w2[i], ov, a2);
      a3 = fmaf(w3[i], ov, a3);
    }
    ob[(size_t)(c + 0) * NTOK] = a0;
    ob[(size_t)(c + 1) * NTOK] = a1;
    ob[(size_t)(c + 2) * NTOK] = a2;
    ob[(size_t)(c + 3) * NTOK] = a3;
  }
}

extern "C" void kernel_launch(void* const* d_in, const int* in_sizes, int n_in,
                              void* d_out, int out_size, void* d_ws, size_t ws_size,
                              hipStream_t stream) {
  const float* x  = (const float*)d_in[0];
  const float* wt = (const float*)d_in[1];
  const float* wp = (const float*)d_in[2];
  const float* wg = (const float*)d_in[3];
  const float* wo = (const float*)d_in[4];
  float* out = (float*)d_out;

  char* ws = (char*)d_ws;
  unsigned short* Q  = (unsigned short*)(ws);                           // 4 MB
  unsigned short* K  = (unsigned short*)(ws + (size_t)4 * 1024 * 1024); // 4 MB
  unsigned short* Vt = (unsigned short*)(ws + (size_t)8 * 1024 * 1024); // 4 MB
  float* Ot          = (float*)(ws + (size_t)12 * 1024 * 1024);         // 8 MB

  qkv_kernel<<<dim3(64, BATCH), 256, 0, stream>>>(x, wt, wp, wg, Q, K, Vt);
  attn_kernel<<<dim3(256), 256, 0, stream>>>(Q, K, Vt, Ot);
  out_kernel<<<dim3(64, BATCH), 256, 0, stream>>>(x, wo, Ot, out);
}

// Round 2
// 279.798 us; speedup vs baseline: 1.7165x; 1.7165x over previous
//
#include <hip/hip_runtime.h>
#include <hip/hip_bf16.h>
#include <cstdint>

#define BATCH 4
#define CDIM 256
#define NTOK 4096
#define IDIM 128

typedef __attribute__((ext_vector_type(4))) float f32x4;
typedef __attribute__((ext_vector_type(8))) short short8;

static __device__ __forceinline__ unsigned cvt_pk(float lo, float hi) {
  unsigned r;
  asm("v_cvt_pk_bf16_f32 %0, %1, %2" : "=v"(r) : "v"(lo), "v"(hi));
  return r;
}
static __device__ __forceinline__ float bf2f(unsigned short u) {
  union { unsigned u; float f; } v;
  v.u = (unsigned)u << 16;
  return v.f;
}

// ---------------------------------------------------------------------------
// Phase 0: cast all weights fp32 -> bf16 into one buffer.
// Wb layout: [theta 32768][phi 32768][g 32768][wo 32768] bf16, row-major as src.
// ---------------------------------------------------------------------------
__global__ __launch_bounds__(256) void cast_w_kernel(
    const float* __restrict__ wt, const float* __restrict__ wp,
    const float* __restrict__ wg, const float* __restrict__ wo,
    unsigned short* __restrict__ Wb)
{
  int id = blockIdx.x * 256 + threadIdx.x;  // 32768 float4 units
  int seg = id >> 13;                        // 8192 units per segment
  int off = (id & 8191) * 4;
  const float* src = seg == 0 ? wt : seg == 1 ? wp : seg == 2 ? wg : wo;
  float4 v = *(const float4*)&src[off];
  uint2 u = make_uint2(cvt_pk(v.x, v.y), cvt_pk(v.z, v.w));
  *(uint2*)&Wb[seg * 32768 + off] = u;
}

// ---------------------------------------------------------------------------
// Phase 1: QKV projection, MFMA.
//   D[n][i] = sum_c Xt[n][c] * W[i][c];  A = Xt (LDS, swizzled), B = W (global bf16)
// Block: 768 thr = 12 waves = (proj 0..2) x (nsub 0..3); tile 64 n x 128 i/proj.
// Q,K stored [b][n][i] (i-contig, via LDS repack); Vt stored [b][i][n] (direct).
// ---------------------------------------------------------------------------
__global__ __launch_bounds__(768) void qkv_kernel(
    const float* __restrict__ x, const unsigned short* __restrict__ Wb,
    unsigned short* __restrict__ Q, unsigned short* __restrict__ K,
    unsigned short* __restrict__ Vt)
{
  __shared__ __align__(16) unsigned short xt[64 * 256];     // 32KB, xt[n][c] swizzled
  __shared__ __align__(16) unsigned short sc[8][16 * 128];  // 32KB, per-wave Q/K repack

  const int b = blockIdx.y;
  const int n0 = blockIdx.x * 64;
  const int t = threadIdx.x;
  const float* xb = x + (size_t)b * CDIM * NTOK;

  // stage x^T as bf16: elem [n][c] at byte n*512 + ((c*2) ^ ((n&15)<<4))
  for (int it = 0; it < 3; ++it) {
    int u = it * 768 + t;
    if (u < 2048) {
      int c0 = (u >> 4) * 2;
      int n4 = (u & 15) * 4;
      float4 va = *(const float4*)&xb[(size_t)c0 * NTOK + n0 + n4];
      float4 vb = *(const float4*)&xb[(size_t)(c0 + 1) * NTOK + n0 + n4];
      const float* pa = (const float*)&va;
      const float* pb = (const float*)&vb;
#pragma unroll
      for (int j = 0; j < 4; ++j) {
        int n = n4 + j;
        unsigned pk = cvt_pk(pa[j], pb[j]);   // lo = x[c0][n], hi = x[c0+1][n]
        *(unsigned*)((char*)xt + n * 512 + ((c0 * 2) ^ ((n & 15) << 4))) = pk;
      }
    }
  }
  __syncthreads();

  const int lane = t & 63;
  const int wv = __builtin_amdgcn_readfirstlane(t >> 6);
  const int nsub = wv & 3, proj = wv >> 2;
  const int cl = lane & 15, g = lane >> 4;
  const unsigned short* Wp = Wb + proj * (IDIM * CDIM);

  f32x4 acc[8];
#pragma unroll
  for (int i = 0; i < 8; ++i) acc[i] = (f32x4){0.f, 0.f, 0.f, 0.f};

  const int nrow = nsub * 16 + cl;
  const int swz = (nrow & 15) << 4;
#pragma unroll
  for (int kc = 0; kc < 8; ++kc) {
    int cb = kc * 32 + g * 8;
    short8 af = *(const short8*)((const char*)xt + nrow * 512 + ((cb * 2) ^ swz));
#pragma unroll
    for (int is = 0; is < 8; ++is) {
      short8 bf = *(const short8*)&Wp[(size_t)(is * 16 + cl) * CDIM + cb];
      acc[is] = __builtin_amdgcn_mfma_f32_16x16x32_bf16(af, bf, acc[is], 0, 0, 0);
    }
  }

  if (proj < 2) {
    // repack D (i-scattered per lane) -> i-contiguous rows via wave-local LDS
    unsigned short* scw = sc[wv];  // wv in 0..7 for proj<2
#pragma unroll
    for (int is = 0; is < 8; ++is)
#pragma unroll
      for (int r = 0; r < 4; ++r) {
        int nl = g * 4 + r;
        int i2 = (is * 16 + cl) * 2;
        *(unsigned short*)((char*)scw + nl * 256 + (i2 ^ ((nl & 15) << 4))) =
            (unsigned short)cvt_pk(acc[is][r], 0.f);
      }
    unsigned short* dst = (proj == 0 ? Q : K) +
        ((size_t)b * NTOK + n0 + nsub * 16) * IDIM;
    int nr = lane >> 2;
    int swr = (nr & 15) << 4;
#pragma unroll
    for (int j = 0; j < 4; ++j) {
      int ch = (lane & 3) + 4 * j;
      short8 v = *(const short8*)((const char*)scw + nr * 256 + ((ch * 16) ^ swr));
      *(short8*)&dst[(size_t)nr * IDIM + ch * 8] = v;
    }
  } else {
    // Vt[b][i][n]: lane's 4 acc values are consecutive n at fixed i -> 8B stores
    unsigned short* dstV = Vt + (size_t)b * IDIM * NTOK + n0 + nsub * 16 + g * 4;
#pragma unroll
    for (int is = 0; is < 8; ++is) {
      uint2 u = make_uint2(cvt_pk(acc[is][0], acc[is][1]),
                           cvt_pk(acc[is][2], acc[is][3]));
      *(uint2*)&dstV[(size_t)(is * 16 + cl) * NTOK] = u;
    }
  }
}

// ---------------------------------------------------------------------------
// Phase 2: flash attention, swapped-operand, in-block 4-way m-split.
// Block: 1024 thr = 16 waves = (ms 0..3) x (ns 0..3); 64 n per block, 16 n/wave,
// m-chunk 1024/wave. Partials merged in LDS. O out: [b][n][i] bf16.
// ---------------------------------------------------------------------------
__global__ __launch_bounds__(1024, 4) void attn_kernel(
    const unsigned short* __restrict__ Q, const unsigned short* __restrict__ K,
    const unsigned short* __restrict__ Vt, unsigned short* __restrict__ O)
{
  __shared__ __align__(16) unsigned short osb[4][64][136];  // 68KB bf16 partial O
  __shared__ float oml[4][2][64];                           // M, L per split per n

  const int bid = blockIdx.x;                 // 256 blocks; bid&7 = XCD
  const int b = (bid & 7) >> 1;               // batch pinned to an XCD pair
  const int nblk = (bid & 1) * 32 + (bid >> 3);
  const int n0b = nblk * 64;
  const int t = threadIdx.x;
  const int lane = t & 63;
  const int wv = __builtin_amdgcn_readfirstlane(t >> 6);
  const int ns = wv & 3, ms = wv >> 2;
  const int n0 = n0b + ns * 16;
  const int cl = lane & 15, g = lane >> 4;

  const unsigned short* Qb = Q + ((size_t)b * NTOK + n0 + cl) * IDIM + g * 8;
  short8 q[4];
#pragma unroll
  for (int kc = 0; kc < 4; ++kc) q[kc] = *(const short8*)(Qb + kc * 32);

  const unsigned short* Kb = K + (size_t)b * NTOK * IDIM;
  const unsigned short* Vb = Vt + (size_t)b * IDIM * NTOK;

  f32x4 o[8];
#pragma unroll
  for (int i = 0; i < 8; ++i) o[i] = (f32x4){0.f, 0.f, 0.f, 0.f};
  float M = -3.0e38f, L = 0.f;

  const int l0 = ((g * 32 + cl) & 63) * 4;
  const int l1 = ((g * 32 + 16 + cl) & 63) * 4;
  const bool lowg = (g < 2);
  const int mend = ms * 1024 + 1024;

  for (int m0 = ms * 1024; m0 < mend; m0 += 32) {
    // ---- St = K . Q^T -----------------------------------------------------
    const unsigned short* kp = Kb + (size_t)(m0 + cl) * IDIM + g * 8;
    f32x4 s0 = {0.f, 0.f, 0.f, 0.f}, s1 = {0.f, 0.f, 0.f, 0.f};
    __builtin_amdgcn_s_setprio(1);
#pragma unroll
    for (int kc = 0; kc < 4; ++kc) {
      short8 ka = *(const short8*)(kp + kc * 32);
      s0 = __builtin_amdgcn_mfma_f32_16x16x32_bf16(ka, q[kc], s0, 0, 0, 0);
    }
#pragma unroll
    for (int kc = 0; kc < 4; ++kc) {
      short8 ka = *(const short8*)(kp + 16 * IDIM + kc * 32);
      s1 = __builtin_amdgcn_mfma_f32_16x16x32_bf16(ka, q[kc], s1, 0, 0, 0);
    }
    __builtin_amdgcn_s_setprio(0);

    // ---- online softmax over m, defer-max (T13) ---------------------------
    float sm = fmaxf(fmaxf(fmaxf(s0[0], s0[1]), fmaxf(s0[2], s0[3])),
                     fmaxf(fmaxf(s1[0], s1[1]), fmaxf(s1[2], s1[3])));
    sm = fmaxf(sm, __shfl_xor(sm, 16));
    sm = fmaxf(sm, __shfl_xor(sm, 32));
    if (!__all(sm <= M + 8.f)) {
      float Mn = fmaxf(M, sm);
      float scl = __expf(M - Mn);
      M = Mn;
      L *= scl;
#pragma unroll
      for (int i = 0; i < 8; ++i) o[i] *= scl;
    }
    float p0[4], p1[4];
#pragma unroll
    for (int r = 0; r < 4; ++r) {
      p0[r] = __expf(s0[r] - M);
      p1[r] = __expf(s1[r] - M);
    }
    float ls = (p0[0] + p0[1] + p0[2] + p0[3]) + (p1[0] + p1[1] + p1[2] + p1[3]);
    ls += __shfl_xor(ls, 16);
    ls += __shfl_xor(ls, 32);
    L += ls;

    // ---- P^T -> bf16 B-fragment (cvt_pk + ds_bpermute) --------------------
    unsigned A0 = cvt_pk(p0[0], p0[1]), A1 = cvt_pk(p0[2], p0[3]);
    unsigned B0 = cvt_pk(p1[0], p1[1]), B1 = cvt_pk(p1[2], p1[3]);
    int w0a = __builtin_amdgcn_ds_bpermute(l0, (int)A0);
    int w0b = __builtin_amdgcn_ds_bpermute(l0, (int)B0);
    int w1a = __builtin_amdgcn_ds_bpermute(l0, (int)A1);
    int w1b = __builtin_amdgcn_ds_bpermute(l0, (int)B1);
    int w2a = __builtin_amdgcn_ds_bpermute(l1, (int)A0);
    int w2b = __builtin_amdgcn_ds_bpermute(l1, (int)B0);
    int w3a = __builtin_amdgcn_ds_bpermute(l1, (int)A1);
    int w3b = __builtin_amdgcn_ds_bpermute(l1, (int)B1);
    union { int u[4]; short8 s; } pf;
    pf.u[0] = lowg ? w0a : w0b;
    pf.u[1] = lowg ? w1a : w1b;
    pf.u[2] = lowg ? w2a : w2b;
    pf.u[3] = lowg ? w3a : w3b;

    // ---- Ot += Vt . P^T ---------------------------------------------------
    const unsigned short* vp = Vb + (size_t)cl * NTOK + m0 + g * 8;
    __builtin_amdgcn_s_setprio(1);
#pragma unroll
    for (int is = 0; is < 8; ++is) {
      short8 va = *(const short8*)(vp + (size_t)(is * 16) * NTOK);
      o[is] = __builtin_amdgcn_mfma_f32_16x16x32_bf16(va, pf.s, o[is], 0, 0, 0);
    }
    __builtin_amdgcn_s_setprio(0);
  }

  // ---- write partials -----------------------------------------------------
  {
    unsigned short* orow = &osb[ms][ns * 16 + cl][0];
#pragma unroll
    for (int is = 0; is < 8; ++is) {
      uint2 u = make_uint2(cvt_pk(o[is][0], o[is][1]), cvt_pk(o[is][2], o[is][3]));
      *(uint2*)&orow[is * 16 + g * 4] = u;
    }
    if (lane < 16) {
      oml[ms][0][ns * 16 + lane] = M;
      oml[ms][1][ns * 16 + lane] = L;
    }
  }
  __syncthreads();

  // ---- combine 4 m-splits, normalize, store O[b][n][i] bf16 ---------------
  {
    int n = t >> 4;
    int i0 = (t & 15) * 8;
    float M0 = oml[0][0][n], M1 = oml[1][0][n], M2 = oml[2][0][n], M3 = oml[3][0][n];
    float Mx = fmaxf(fmaxf(M0, M1), fmaxf(M2, M3));
    float w0 = __expf(M0 - Mx), w1 = __expf(M1 - Mx);
    float w2 = __expf(M2 - Mx), w3 = __expf(M3 - Mx);
    float Lx = w0 * oml[0][1][n] + w1 * oml[1][1][n] +
               w2 * oml[2][1][n] + w3 * oml[3][1][n];
    float rinv = 1.f / Lx;
    float acc[8];
    const short8 v0 = *(const short8*)&osb[0][n][i0];
    const short8 v1 = *(const short8*)&osb[1][n][i0];
    const short8 v2 = *(const short8*)&osb[2][n][i0];
    const short8 v3 = *(const short8*)&osb[3][n][i0];
#pragma unroll
    for (int e = 0; e < 8; ++e) {
      acc[e] = (w0 * bf2f((unsigned short)v0[e]) + w1 * bf2f((unsigned short)v1[e]) +
                w2 * bf2f((unsigned short)v2[e]) + w3 * bf2f((unsigned short)v3[e])) * rinv;
    }
    union { unsigned u[4]; short8 s; } r;
#pragma unroll
    for (int jp = 0; jp < 4; ++jp) r.u[jp] = cvt_pk(acc[2 * jp], acc[2 * jp + 1]);
    unsigned short* dst = O + ((size_t)b * NTOK + n0b + n) * IDIM + i0;
    *(short8*)dst = r.s;
  }
}

// ---------------------------------------------------------------------------
// Phase 3: out[b][c][n] = x[b][c][n] + sum_i wo[c][i] * O[b][n][i], MFMA.
// Block: 256 thr = 4 waves (c-range 64 each); tile 32 n x 256 c. All operands
// fragment-load directly from global (wo bf16, O bf16).
// ---------------------------------------------------------------------------
__global__ __launch_bounds__(256) void out_kernel(
    const float* __restrict__ x, const unsigned short* __restrict__ Wb,
    const unsigned short* __restrict__ O, float* __restrict__ out)
{
  const unsigned short* wo = Wb + 3 * 32768;
  const int b = blockIdx.y;
  const int n0 = blockIdx.x * 32;
  const int t = threadIdx.x;
  const int lane = t & 63;
  const int wv = __builtin_amdgcn_readfirstlane(t >> 6);
  const int cl = lane & 15, g = lane >> 4;

  f32x4 acc[4][2];
#pragma unroll
  for (int cs = 0; cs < 4; ++cs)
#pragma unroll
    for (int nsb = 0; nsb < 2; ++nsb) acc[cs][nsb] = (f32x4){0.f, 0.f, 0.f, 0.f};

#pragma unroll
  for (int kc = 0; kc < 4; ++kc) {
    int i0 = kc * 32 + g * 8;
    short8 bf[2];
#pragma unroll
    for (int nsb = 0; nsb < 2; ++nsb)
      bf[nsb] = *(const short8*)&O[((size_t)b * NTOK + n0 + nsb * 16 + cl) * IDIM + i0];
#pragma unroll
    for (int cs = 0; cs < 4; ++cs) {
      short8 af = *(const short8*)&wo[(size_t)(wv * 64 + cs * 16 + cl) * IDIM + i0];
#pragma unroll
      for (int nsb = 0; nsb < 2; ++nsb)
        acc[cs][nsb] = __builtin_amdgcn_mfma_f32_16x16x32_bf16(af, bf[nsb], acc[cs][nsb], 0, 0, 0);
    }
  }

  const float* xb = x + (size_t)b * CDIM * NTOK;
  float* ob = out + (size_t)b * CDIM * NTOK;
#pragma unroll
  for (int cs = 0; cs < 4; ++cs)
#pragma unroll
    for (int nsb = 0; nsb < 2; ++nsb)
#pragma unroll
      for (int r = 0; r < 4; ++r) {
        int c = wv * 64 + cs * 16 + g * 4 + r;
        int n = n0 + nsb * 16 + cl;
        ob[(size_t)c * NTOK + n] = xb[(size_t)c * NTOK + n] + acc[cs][nsb][r];
      }
}

extern "C" void kernel_launch(void* const* d_in, const int* in_sizes, int n_in,
                              void* d_out, int out_size, void* d_ws, size_t ws_size,
                              hipStream_t stream) {
  const float* x  = (const float*)d_in[0];
  const float* wt = (const float*)d_in[1];
  const float* wp = (const float*)d_in[2];
  const float* wg = (const float*)d_in[3];
  const float* wo = (const float*)d_in[4];
  float* outp = (float*)d_out;

  char* ws = (char*)d_ws;
  unsigned short* Wb  = (unsigned short*)(ws);                         // 256KB
  unsigned short* Qd  = (unsigned short*)(ws + (size_t)1  * (1 << 20)); // 4MB
  unsigned short* Kd  = (unsigned short*)(ws + (size_t)5  * (1 << 20)); // 4MB
  unsigned short* Vtd = (unsigned short*)(ws + (size_t)9  * (1 << 20)); // 4MB
  unsigned short* Od  = (unsigned short*)(ws + (size_t)13 * (1 << 20)); // 4MB

  cast_w_kernel<<<128, 256, 0, stream>>>(wt, wp, wg, wo, Wb);
  qkv_kernel<<<dim3(64, BATCH), 768, 0, stream>>>(x, Wb, Qd, Kd, Vtd);
  attn_kernel<<<256, 1024, 0, stream>>>(Qd, Kd, Vtd, Od);
  out_kernel<<<dim3(128, BATCH), 256, 0, stream>>>(x, Wb, Od, outp);
}

// Round 3
// 123.801 us; speedup vs baseline: 3.8795x; 2.2601x over previous
//
#include <hip/hip_runtime.h>
#include <hip/hip_bf16.h>
#include <cstdint>

#define BATCH 4
#define CDIM 256
#define NTOK 4096
#define IDIM 128

typedef __attribute__((ext_vector_type(4))) float f32x4;
typedef __attribute__((ext_vector_type(16))) float f32x16;
typedef __attribute__((ext_vector_type(8))) short short8;

static __device__ __forceinline__ unsigned cvt_pk(float lo, float hi) {
  unsigned r;
  asm("v_cvt_pk_bf16_f32 %0, %1, %2" : "=v"(r) : "v"(lo), "v"(hi));
  return r;
}
static __device__ __forceinline__ float bf2f(unsigned short u) {
  union { unsigned u; float f; } v;
  v.u = (unsigned)u << 16;
  return v.f;
}
// async global->LDS, 16B per lane. LDS dest must be wave-uniform base + lane*16.
static __device__ __forceinline__ void gl16(const void* g, void* l) {
  __builtin_amdgcn_global_load_lds(
      (const __attribute__((address_space(1))) void*)g,
      (__attribute__((address_space(3))) void*)l, 16, 0, 0);
}

// ---------------------------------------------------------------------------
// Phase 0: cast all weights fp32 -> bf16 into one buffer.
// ---------------------------------------------------------------------------
__global__ __launch_bounds__(256) void cast_w_kernel(
    const float* __restrict__ wt, const float* __restrict__ wp,
    const float* __restrict__ wg, const float* __restrict__ wo,
    unsigned short* __restrict__ Wb)
{
  int id = blockIdx.x * 256 + threadIdx.x;  // 32768 float4 units
  int seg = id >> 13;
  int off = (id & 8191) * 4;
  const float* src = seg == 0 ? wt : seg == 1 ? wp : seg == 2 ? wg : wo;
  float4 v = *(const float4*)&src[off];
  uint2 u = make_uint2(cvt_pk(v.x, v.y), cvt_pk(v.z, v.w));
  *(uint2*)&Wb[seg * 32768 + off] = u;
}

// ---------------------------------------------------------------------------
// Phase 1: QKV projection, MFMA (unchanged from R2).
// ---------------------------------------------------------------------------
__global__ __launch_bounds__(768) void qkv_kernel(
    const float* __restrict__ x, const unsigned short* __restrict__ Wb,
    unsigned short* __restrict__ Q, unsigned short* __restrict__ K,
    unsigned short* __restrict__ Vt)
{
  __shared__ __align__(16) unsigned short xt[64 * 256];
  __shared__ __align__(16) unsigned short sc[8][16 * 128];

  const int b = blockIdx.y;
  const int n0 = blockIdx.x * 64;
  const int t = threadIdx.x;
  const float* xb = x + (size_t)b * CDIM * NTOK;

  for (int it = 0; it < 3; ++it) {
    int u = it * 768 + t;
    if (u < 2048) {
      int c0 = (u >> 4) * 2;
      int n4 = (u & 15) * 4;
      float4 va = *(const float4*)&xb[(size_t)c0 * NTOK + n0 + n4];
      float4 vb = *(const float4*)&xb[(size_t)(c0 + 1) * NTOK + n0 + n4];
      const float* pa = (const float*)&va;
      const float* pb = (const float*)&vb;
#pragma unroll
      for (int j = 0; j < 4; ++j) {
        int n = n4 + j;
        unsigned pk = cvt_pk(pa[j], pb[j]);
        *(unsigned*)((char*)xt + n * 512 + ((c0 * 2) ^ ((n & 15) << 4))) = pk;
      }
    }
  }
  __syncthreads();

  const int lane = t & 63;
  const int wv = __builtin_amdgcn_readfirstlane(t >> 6);
  const int nsub = wv & 3, proj = wv >> 2;
  const int cl = lane & 15, g = lane >> 4;
  const unsigned short* Wp = Wb + proj * (IDIM * CDIM);

  f32x4 acc[8];
#pragma unroll
  for (int i = 0; i < 8; ++i) acc[i] = (f32x4){0.f, 0.f, 0.f, 0.f};

  const int nrow = nsub * 16 + cl;
  const int swz = (nrow & 15) << 4;
#pragma unroll
  for (int kc = 0; kc < 8; ++kc) {
    int cb = kc * 32 + g * 8;
    short8 af = *(const short8*)((const char*)xt + nrow * 512 + ((cb * 2) ^ swz));
#pragma unroll
    for (int is = 0; is < 8; ++is) {
      short8 bf = *(const short8*)&Wp[(size_t)(is * 16 + cl) * CDIM + cb];
      acc[is] = __builtin_amdgcn_mfma_f32_16x16x32_bf16(af, bf, acc[is], 0, 0, 0);
    }
  }

  if (proj < 2) {
    unsigned short* scw = sc[wv];
#pragma unroll
    for (int is = 0; is < 8; ++is)
#pragma unroll
      for (int r = 0; r < 4; ++r) {
        int nl = g * 4 + r;
        int i2 = (is * 16 + cl) * 2;
        *(unsigned short*)((char*)scw + nl * 256 + (i2 ^ ((nl & 15) << 4))) =
            (unsigned short)cvt_pk(acc[is][r], 0.f);
      }
    unsigned short* dst = (proj == 0 ? Q : K) +
        ((size_t)b * NTOK + n0 + nsub * 16) * IDIM;
    int nr = lane >> 2;
    int swr = (nr & 15) << 4;
#pragma unroll
    for (int j = 0; j < 4; ++j) {
      int ch = (lane & 3) + 4 * j;
      short8 v = *(const short8*)((const char*)scw + nr * 256 + ((ch * 16) ^ swr));
      *(short8*)&dst[(size_t)nr * IDIM + ch * 8] = v;
    }
  } else {
    unsigned short* dstV = Vt + (size_t)b * IDIM * NTOK + n0 + nsub * 16 + g * 4;
#pragma unroll
    for (int is = 0; is < 8; ++is) {
      uint2 u = make_uint2(cvt_pk(acc[is][0], acc[is][1]),
                           cvt_pk(acc[is][2], acc[is][3]));
      *(uint2*)&dstV[(size_t)(is * 16 + cl) * NTOK] = u;
    }
  }
}

// ---------------------------------------------------------------------------
// Phase 2: flash attention v3. 32x32x16 MFMA, LDS-staged K/V tiles.
// Block: 512 thr = 8 waves = 2 n-waves(32n) x 4 m-streams(1024m each).
// Per m-iter (KVBLK=32): stage next K/V tile (global_load_lds, XOR-preswizzled
// source), compute QK^T (32x32), in-register softmax (col = lane), bpermute
// P-repack, PV. In-block LDS combine of the 4 m-split partials.
// ---------------------------------------------------------------------------
__global__ __launch_bounds__(512) void attn_kernel(
    const unsigned short* __restrict__ Q, const unsigned short* __restrict__ K,
    const unsigned short* __restrict__ Vt, unsigned short* __restrict__ O)
{
  __shared__ __align__(16) unsigned short kls[4][2][32 * 128];   // 64KB
  __shared__ __align__(16) unsigned short vls[4][2][128 * 32];   // 64KB
  __shared__ float oml[4][2][64];                                 // 2KB

  const int bid = blockIdx.x;                 // 256 blocks; bid&7 = XCD
  const int b = (bid >> 1) & 3;               // batch pinned to an XCD pair
  const int nblk = (bid >> 3) * 2 + (bid & 1);
  const int n0b = nblk * 64;
  const int t = threadIdx.x;
  const int lane = t & 63;
  const int wv = __builtin_amdgcn_readfirstlane(t >> 6);
  const int nw = wv & 1, ms = wv >> 1;
  const int c32 = lane & 31, hl = lane >> 5;
  const int p = nw * 64 + lane;               // tid within the 2-wave m-stream

  const unsigned short* Kb = K + (size_t)b * NTOK * IDIM;
  const unsigned short* Vb = Vt + (size_t)b * IDIM * NTOK;

  // Q fragments (B operand, 32x32x16): col=n (lane&31), k=i (kc*16+hl*8+e)
  const unsigned short* Qp =
      Q + ((size_t)b * NTOK + n0b + nw * 32 + c32) * IDIM + hl * 8;
  short8 q[8];
#pragma unroll
  for (int kc = 0; kc < 8; ++kc) q[kc] = *(const short8*)(Qp + kc * 16);

  f32x16 o[4];
#pragma unroll
  for (int it = 0; it < 4; ++it)
#pragma unroll
    for (int e = 0; e < 16; ++e) o[it][e] = 0.f;
  float M = -3.0e38f, L = 0.f;

  const int idxswap = ((lane ^ 32) & 63) * 4;  // bpermute byte index: lane +-32

  // stage K-tile [32 rows][128 i] (XOR-chunk (r&7)) and V-tile [128 i][32 m]
  // (XOR-chunk (i&3)); dest is linear (base + lane*16), source pre-swizzled.
#define STAGE(cb, m0_)                                                        \
  {                                                                           \
    _Pragma("unroll")                                                         \
    for (int u = 0; u < 4; ++u) {                                             \
      int idx = p + 128 * u;                                                  \
      int r = idx >> 4, ch = idx & 15;                                        \
      gl16(Kb + (size_t)(m0_ + r) * IDIM + ((ch ^ (r & 7)) * 8),              \
           (void*)&kls[ms][cb][idx * 8]);                                     \
    }                                                                         \
    _Pragma("unroll")                                                         \
    for (int u = 0; u < 4; ++u) {                                             \
      int idx = p + 128 * u;                                                  \
      int i = idx >> 2, mc = idx & 3;                                         \
      gl16(Vb + (size_t)i * NTOK + (m0_) + ((mc ^ (i & 3)) * 8),              \
           (void*)&vls[ms][cb][idx * 8]);                                     \
    }                                                                         \
  }

  const int mbase = ms * 1024;
  int cur = 0;
  STAGE(0, mbase)
  __syncthreads();

  for (int itn = 0; itn < 32; ++itn) {
    if (itn < 31) STAGE(cur ^ 1, mbase + (itn + 1) * 32)

    // ---- St = K . Q^T (32m x 32n), A=K from LDS ---------------------------
    const char* kbuf = (const char*)kls[ms][cur];
    f32x16 st;
#pragma unroll
    for (int e = 0; e < 16; ++e) st[e] = 0.f;
    __builtin_amdgcn_s_setprio(1);
#pragma unroll
    for (int kc = 0; kc < 8; ++kc) {
      short8 kf = *(const short8*)(kbuf + c32 * 256 +
                                   ((kc * 32 + hl * 16) ^ ((c32 & 7) << 4)));
      st = __builtin_amdgcn_mfma_f32_32x32x16_bf16(kf, q[kc], st, 0, 0, 0);
    }
    __builtin_amdgcn_s_setprio(0);

    // ---- online softmax over m (col n = lane&31; rows split lane/lane+32) -
    float sm = st[0];
#pragma unroll
    for (int e = 1; e < 16; ++e) sm = fmaxf(sm, st[e]);
    sm = fmaxf(sm, __shfl_xor(sm, 32));
    if (!__all(sm <= M + 8.f)) {            // defer-max (T13)
      float Mn = fmaxf(M, sm);
      float scl = __expf(M - Mn);
      M = Mn;
      L *= scl;
#pragma unroll
      for (int it = 0; it < 4; ++it)
#pragma unroll
        for (int e = 0; e < 16; ++e) o[it][e] *= scl;
    }
    float pr[16];
#pragma unroll
    for (int e = 0; e < 16; ++e) pr[e] = __expf(st[e] - M);
    float ls = 0.f;
#pragma unroll
    for (int e = 0; e < 16; ++e) ls += pr[e];
    ls += __shfl_xor(ls, 32);
    L += ls;

    // ---- P^T -> B-fragments (2 x k16), cvt_pk + lane+-32 bpermute ---------
    // reg r -> m = (r&3) + 8*(r>>2) + 4*hl (+ kt*16 for r>=8)
    short8 pf[2];
#pragma unroll
    for (int kt = 0; kt < 2; ++kt) {
      unsigned a0 = cvt_pk(pr[kt * 8 + 0], pr[kt * 8 + 1]);
      unsigned a1 = cvt_pk(pr[kt * 8 + 2], pr[kt * 8 + 3]);
      unsigned a2 = cvt_pk(pr[kt * 8 + 4], pr[kt * 8 + 5]);
      unsigned a3 = cvt_pk(pr[kt * 8 + 6], pr[kt * 8 + 7]);
      unsigned x0 = (unsigned)__builtin_amdgcn_ds_bpermute(idxswap, (int)a0);
      unsigned x1 = (unsigned)__builtin_amdgcn_ds_bpermute(idxswap, (int)a1);
      unsigned x2 = (unsigned)__builtin_amdgcn_ds_bpermute(idxswap, (int)a2);
      unsigned x3 = (unsigned)__builtin_amdgcn_ds_bpermute(idxswap, (int)a3);
      union { unsigned u[4]; short8 s; } w;
      w.u[0] = hl ? x2 : a0;   // W0: lo=a0, hi=lo-lane's a2
      w.u[1] = hl ? x3 : a1;
      w.u[2] = hl ? a2 : x0;   // W2: lo=hi-lane's a0, hi=a2
      w.u[3] = hl ? a3 : x1;
      pf[kt] = w.s;
    }

    // ---- Ot += Vt . P^T (4 i-tiles x 2 k-halves) --------------------------
    const char* vbuf = (const char*)vls[ms][cur];
    __builtin_amdgcn_s_setprio(1);
#pragma unroll
    for (int it = 0; it < 4; ++it) {
#pragma unroll
      for (int kt = 0; kt < 2; ++kt) {
        int row = it * 32 + c32;
        short8 vf = *(const short8*)(vbuf + row * 64 +
                                     ((kt * 32 + hl * 16) ^ ((row & 3) << 4)));
        o[it] = __builtin_amdgcn_mfma_f32_32x32x16_bf16(vf, pf[kt], o[it], 0, 0, 0);
      }
    }
    __builtin_amdgcn_s_setprio(0);

    __syncthreads();
    cur ^= 1;
  }

  // ---- write partials (reuse kls as [4 ms][64 n][128 i] bf16) -------------
  unsigned short* osb = &kls[0][0][0];
  {
    int n_l = nw * 32 + c32;
    unsigned short* orow = osb + ms * 8192 + n_l * 128;
#pragma unroll
    for (int it = 0; it < 4; ++it)
#pragma unroll
      for (int g2 = 0; g2 < 4; ++g2) {
        int ib = it * 32 + 8 * g2 + 4 * hl;
        uint2 u2 = make_uint2(cvt_pk(o[it][4 * g2 + 0], o[it][4 * g2 + 1]),
                              cvt_pk(o[it][4 * g2 + 2], o[it][4 * g2 + 3]));
        *(uint2*)&orow[ib] = u2;
      }
    if (hl == 0) {
      oml[ms][0][n_l] = M;
      oml[ms][1][n_l] = L;
    }
  }
  __syncthreads();

  // ---- combine 4 m-splits, normalize, store O[b][n][i] bf16 ---------------
  {
    int n_l = t >> 3;
    int i0 = (t & 7) * 16;
    float M0 = oml[0][0][n_l], M1 = oml[1][0][n_l];
    float M2 = oml[2][0][n_l], M3 = oml[3][0][n_l];
    float Mx = fmaxf(fmaxf(M0, M1), fmaxf(M2, M3));
    float wsv[4];
    wsv[0] = __expf(M0 - Mx); wsv[1] = __expf(M1 - Mx);
    wsv[2] = __expf(M2 - Mx); wsv[3] = __expf(M3 - Mx);
    float Lx = wsv[0] * oml[0][1][n_l] + wsv[1] * oml[1][1][n_l] +
               wsv[2] * oml[2][1][n_l] + wsv[3] * oml[3][1][n_l];
    float rinv = 1.f / Lx;
    float acc[16];
#pragma unroll
    for (int e = 0; e < 16; ++e) acc[e] = 0.f;
#pragma unroll
    for (int s = 0; s < 4; ++s) {
      const short8 va = *(const short8*)&osb[s * 8192 + n_l * 128 + i0];
      const short8 vb2 = *(const short8*)&osb[s * 8192 + n_l * 128 + i0 + 8];
#pragma unroll
      for (int e = 0; e < 8; ++e) {
        acc[e]     += wsv[s] * bf2f((unsigned short)va[e]);
        acc[8 + e] += wsv[s] * bf2f((unsigned short)vb2[e]);
      }
    }
    union { unsigned u[8]; short8 s[2]; } r;
#pragma unroll
    for (int jp = 0; jp < 8; ++jp)
      r.u[jp] = cvt_pk(acc[2 * jp] * rinv, acc[2 * jp + 1] * rinv);
    unsigned short* dst = O + ((size_t)b * NTOK + n0b + n_l) * IDIM + i0;
    *(short8*)dst = r.s[0];
    *(short8*)(dst + 8) = r.s[1];
  }
#undef STAGE
}

// ---------------------------------------------------------------------------
// Phase 3: out[b][c][n] = x[b][c][n] + sum_i wo[c][i] * O[b][n][i], MFMA.
// ---------------------------------------------------------------------------
__global__ __launch_bounds__(256) void out_kernel(
    const float* __restrict__ x, const unsigned short* __restrict__ Wb,
    const unsigned short* __restrict__ O, float* __restrict__ out)
{
  const unsigned short* wo = Wb + 3 * 32768;
  const int b = blockIdx.y;
  const int n0 = blockIdx.x * 32;
  const int t = threadIdx.x;
  const int lane = t & 63;
  const int wv = __builtin_amdgcn_readfirstlane(t >> 6);
  const int cl = lane & 15, g = lane >> 4;

  f32x4 acc[4][2];
#pragma unroll
  for (int cs = 0; cs < 4; ++cs)
#pragma unroll
    for (int nsb = 0; nsb < 2; ++nsb) acc[cs][nsb] = (f32x4){0.f, 0.f, 0.f, 0.f};

#pragma unroll
  for (int kc = 0; kc < 4; ++kc) {
    int i0 = kc * 32 + g * 8;
    short8 bf[2];
#pragma unroll
    for (int nsb = 0; nsb < 2; ++nsb)
      bf[nsb] = *(const short8*)&O[((size_t)b * NTOK + n0 + nsb * 16 + cl) * IDIM + i0];
#pragma unroll
    for (int cs = 0; cs < 4; ++cs) {
      short8 af = *(const short8*)&wo[(size_t)(wv * 64 + cs * 16 + cl) * IDIM + i0];
#pragma unroll
      for (int nsb = 0; nsb < 2; ++nsb)
        acc[cs][nsb] = __builtin_amdgcn_mfma_f32_16x16x32_bf16(af, bf[nsb], acc[cs][nsb], 0, 0, 0);
    }
  }

  const float* xb = x + (size_t)b * CDIM * NTOK;
  float* ob = out + (size_t)b * CDIM * NTOK;
#pragma unroll
  for (int cs = 0; cs < 4; ++cs)
#pragma unroll
    for (int nsb = 0; nsb < 2; ++nsb)
#pragma unroll
      for (int r = 0; r < 4; ++r) {
        int c = wv * 64 + cs * 16 + g * 4 + r;
        int n = n0 + nsb * 16 + cl;
        ob[(size_t)c * NTOK + n] = xb[(size_t)c * NTOK + n] + acc[cs][nsb][r];
      }
}

extern "C" void kernel_launch(void* const* d_in, const int* in_sizes, int n_in,
                              void* d_out, int out_size, void* d_ws, size_t ws_size,
                              hipStream_t stream) {
  const float* x  = (const float*)d_in[0];
  const float* wt = (const float*)d_in[1];
  const float* wp = (const float*)d_in[2];
  const float* wg = (const float*)d_in[3];
  const float* wo = (const float*)d_in[4];
  float* outp = (float*)d_out;

  char* ws = (char*)d_ws;
  unsigned short* Wb  = (unsigned short*)(ws);                          // 256KB
  unsigned short* Qd  = (unsigned short*)(ws + (size_t)1  * (1 << 20)); // 4MB
  unsigned short* Kd  = (unsigned short*)(ws + (size_t)5  * (1 << 20)); // 4MB
  unsigned short* Vtd = (unsigned short*)(ws + (size_t)9  * (1 << 20)); // 4MB
  unsigned short* Od  = (unsigned short*)(ws + (size_t)13 * (1 << 20)); // 4MB

  cast_w_kernel<<<128, 256, 0, stream>>>(wt, wp, wg, wo, Wb);
  qkv_kernel<<<dim3(64, BATCH), 768, 0, stream>>>(x, Wb, Qd, Kd, Vtd);
  attn_kernel<<<256, 512, 0, stream>>>(Qd, Kd, Vtd, Od);
  out_kernel<<<dim3(128, BATCH), 256, 0, stream>>>(x, Wb, Od, outp);
}

// Round 4
// 87.026 us; speedup vs baseline: 5.5189x; 1.4226x over previous
//
#include <hip/hip_runtime.h>
#include <hip/hip_bf16.h>
#include <cstdint>

#define BATCH 4
#define CDIM 256
#define NTOK 4096
#define IDIM 128

typedef __attribute__((ext_vector_type(4))) float f32x4;
typedef __attribute__((ext_vector_type(16))) float f32x16;
typedef __attribute__((ext_vector_type(8))) short short8;

static __device__ __forceinline__ unsigned cvt_pk(float lo, float hi) {
  unsigned r;
  asm("v_cvt_pk_bf16_f32 %0, %1, %2" : "=v"(r) : "v"(lo), "v"(hi));
  return r;
}
static __device__ __forceinline__ float bf2f(unsigned short u) {
  union { unsigned u; float f; } v;
  v.u = (unsigned)u << 16;
  return v.f;
}
static __device__ __forceinline__ float exp2_f(float x) {
#if __has_builtin(__builtin_amdgcn_exp2f)
  return __builtin_amdgcn_exp2f(x);
#else
  return exp2f(x);
#endif
}
// async global->LDS, 16B per lane. LDS dest = wave-uniform base + lane*16.
static __device__ __forceinline__ void gl16(const void* g, void* l) {
  __builtin_amdgcn_global_load_lds(
      (const __attribute__((address_space(1))) void*)g,
      (__attribute__((address_space(3))) void*)l, 16, 0, 0);
}

// ---------------------------------------------------------------------------
// Phase 0: cast weights fp32 -> bf16, into MFMA-fragment-order layouts.
//  proj p (theta/phi/g):  Wb[((p*32 + (c>>3))*128 + i)*8 + (c&7)] = w[i][c]
//    (theta additionally scaled by log2(e) -> softmax runs in base 2)
//  wo: Wb[98304 + ((i>>3)*256 + c)*8 + (i&7)] = wo[c][i]
// ---------------------------------------------------------------------------
__global__ __launch_bounds__(256) void cast_w_kernel(
    const float* __restrict__ wt, const float* __restrict__ wp,
    const float* __restrict__ wg, const float* __restrict__ wo,
    unsigned short* __restrict__ Wb)
{
  int id = blockIdx.x * 256 + threadIdx.x;   // 0..32767
  if (id < 24576) {
    int pidx = id >> 13;
    int rem = id & 8191;
    int i = rem >> 6, c4 = (rem & 63) * 4;
    const float* src = pidx == 0 ? wt : pidx == 1 ? wp : wg;
    float4 v = *(const float4*)&src[i * 256 + c4];
    float s = (pidx == 0) ? 1.4426950408889634f : 1.0f;
    uint2 u = make_uint2(cvt_pk(v.x * s, v.y * s), cvt_pk(v.z * s, v.w * s));
    *(uint2*)&Wb[(((size_t)pidx * 32 + (c4 >> 3)) * 128 + i) * 8 + (c4 & 7)] = u;
  } else {
    int rem = id - 24576;
    int c = rem >> 5, i4 = (rem & 31) * 4;
    float4 v = *(const float4*)&wo[c * 128 + i4];
    uint2 u = make_uint2(cvt_pk(v.x, v.y), cvt_pk(v.z, v.w));
    *(uint2*)&Wb[98304 + (((size_t)(i4 >> 3) * 256 + c) * 8) + (i4 & 7)] = u;
  }
}

// ---------------------------------------------------------------------------
// Phase 1: QKV projection, MFMA. W fragment loads now fully coalesced.
// ---------------------------------------------------------------------------
__global__ __launch_bounds__(768) void qkv_kernel(
    const float* __restrict__ x, const unsigned short* __restrict__ Wb,
    unsigned short* __restrict__ Q, unsigned short* __restrict__ K,
    unsigned short* __restrict__ Vt)
{
  __shared__ __align__(16) unsigned short xt[64 * 256];
  __shared__ __align__(16) unsigned short sc[8][16 * 128];

  const int b = blockIdx.y;
  const int n0 = blockIdx.x * 64;
  const int t = threadIdx.x;
  const float* xb = x + (size_t)b * CDIM * NTOK;

  for (int it = 0; it < 3; ++it) {
    int u = it * 768 + t;
    if (u < 2048) {
      int c0 = (u >> 4) * 2;
      int n4 = (u & 15) * 4;
      float4 va = *(const float4*)&xb[(size_t)c0 * NTOK + n0 + n4];
      float4 vb = *(const float4*)&xb[(size_t)(c0 + 1) * NTOK + n0 + n4];
      const float* pa = (const float*)&va;
      const float* pb = (const float*)&vb;
#pragma unroll
      for (int j = 0; j < 4; ++j) {
        int n = n4 + j;
        unsigned pk = cvt_pk(pa[j], pb[j]);
        *(unsigned*)((char*)xt + n * 512 + ((c0 * 2) ^ ((n & 15) << 4))) = pk;
      }
    }
  }
  __syncthreads();

  const int lane = t & 63;
  const int wv = __builtin_amdgcn_readfirstlane(t >> 6);
  const int nsub = wv & 3, proj = wv >> 2;
  const int cl = lane & 15, g = lane >> 4;

  f32x4 acc[8];
#pragma unroll
  for (int i = 0; i < 8; ++i) acc[i] = (f32x4){0.f, 0.f, 0.f, 0.f};

  const int nrow = nsub * 16 + cl;
  const int swz = (nrow & 15) << 4;
#pragma unroll
  for (int kc = 0; kc < 8; ++kc) {
    int cb = kc * 32 + g * 8;
    short8 af = *(const short8*)((const char*)xt + nrow * 512 + ((cb * 2) ^ swz));
#pragma unroll
    for (int is = 0; is < 8; ++is) {
      short8 bf = *(const short8*)&Wb[(((size_t)proj * 32 + kc * 4 + g) * 128 +
                                       is * 16 + cl) * 8];
      acc[is] = __builtin_amdgcn_mfma_f32_16x16x32_bf16(af, bf, acc[is], 0, 0, 0);
    }
  }

  if (proj < 2) {
    unsigned short* scw = sc[wv];
#pragma unroll
    for (int is = 0; is < 8; ++is)
#pragma unroll
      for (int r = 0; r < 4; ++r) {
        int nl = g * 4 + r;
        int i2 = (is * 16 + cl) * 2;
        *(unsigned short*)((char*)scw + nl * 256 + (i2 ^ ((nl & 15) << 4))) =
            (unsigned short)cvt_pk(acc[is][r], 0.f);
      }
    unsigned short* dst = (proj == 0 ? Q : K) +
        ((size_t)b * NTOK + n0 + nsub * 16) * IDIM;
    int nr = lane >> 2;
    int swr = (nr & 15) << 4;
#pragma unroll
    for (int j = 0; j < 4; ++j) {
      int ch = (lane & 3) + 4 * j;
      short8 v = *(const short8*)((const char*)scw + nr * 256 + ((ch * 16) ^ swr));
      *(short8*)&dst[(size_t)nr * IDIM + ch * 8] = v;
    }
  } else {
    unsigned short* dstV = Vt + (size_t)b * IDIM * NTOK + n0 + nsub * 16 + g * 4;
#pragma unroll
    for (int is = 0; is < 8; ++is) {
      uint2 u = make_uint2(cvt_pk(acc[is][0], acc[is][1]),
                           cvt_pk(acc[is][2], acc[is][3]));
      *(uint2*)&dstV[(size_t)(is * 16 + cl) * NTOK] = u;
    }
  }
}

// ---------------------------------------------------------------------------
// Phase 2: flash attention v4. Independent 2-wave pipelines.
// Grid 1024 = (4 batch-XCD-pairs) x (64 n-blocks) x (4 m-splits); block=128thr.
// Per iter: [waitcnt+raw barrier] -> prefetch STAGE(t+1) -> compute(t).
// Double-buffered 32KB LDS -> 4 blocks/CU resident. Softmax base-2.
// Partials: unnormalized bf16 O (fragment-order) + (M,L) per n, to workspace.
// ---------------------------------------------------------------------------
__global__ __launch_bounds__(128, 2) void attn_kernel(
    const unsigned short* __restrict__ Q, const unsigned short* __restrict__ K,
    const unsigned short* __restrict__ Vt, unsigned short* __restrict__ Op,
    float2* __restrict__ ML)
{
  __shared__ __align__(16) unsigned short kls[2][32 * 128];  // 16KB
  __shared__ __align__(16) unsigned short vls[2][128 * 32];  // 16KB

  const int bid = blockIdx.x;                  // bid&7 = XCD
  const int b = (bid >> 1) & 3;                // batch pinned to an XCD pair
  const int ms = (bid >> 3) & 3;               // m-split
  const int nblk = (bid >> 5) + (bid & 1) * 32;
  const int t = threadIdx.x;
  const int lane = t & 63;
  const int wv = __builtin_amdgcn_readfirstlane(t >> 6);
  const int n0 = nblk * 64 + wv * 32;
  const int c32 = lane & 31, hl = lane >> 5;
  const int p = t;                             // 0..127 staging id

  const unsigned short* Kb = K + (size_t)b * NTOK * IDIM;
  const unsigned short* Vb = Vt + (size_t)b * IDIM * NTOK;

  // Q fragments (B operand, 32x32x16): col=n (lane&31), k=i
  const unsigned short* Qp = Q + ((size_t)b * NTOK + n0 + c32) * IDIM + hl * 8;
  short8 q[8];
#pragma unroll
  for (int kc = 0; kc < 8; ++kc) q[kc] = *(const short8*)(Qp + kc * 16);

  f32x16 o[4];
#pragma unroll
  for (int it = 0; it < 4; ++it)
#pragma unroll
    for (int e = 0; e < 16; ++e) o[it][e] = 0.f;
  float M = -3.0e38f, L = 0.f;

  const int idxswap = ((lane ^ 32) & 63) * 4;

#define STAGE(cb, m0_)                                                        \
  {                                                                           \
    _Pragma("unroll")                                                         \
    for (int u = 0; u < 4; ++u) {                                             \
      int idx = p + 128 * u;                                                  \
      int r = idx >> 4, ch = idx & 15;                                        \
      gl16(Kb + (size_t)((m0_) + r) * IDIM + ((ch ^ (r & 7)) * 8),            \
           (void*)&kls[cb][idx * 8]);                                         \
    }                                                                         \
    _Pragma("unroll")                                                         \
    for (int u = 0; u < 4; ++u) {                                             \
      int idx = p + 128 * u;                                                  \
      int i = idx >> 2, mc = idx & 3;                                         \
      gl16(Vb + (size_t)i * NTOK + (m0_) + ((mc ^ (i & 3)) * 8),              \
           (void*)&vls[cb][idx * 8]);                                         \
    }                                                                         \
  }

  const int mbase = ms * 1024;
  STAGE(0, mbase)

  for (int tt = 0; tt < 32; ++tt) {
    // own staged loads landed + own LDS reads drained, then join both waves.
    asm volatile("s_waitcnt vmcnt(0) lgkmcnt(0)\n\ts_barrier" ::: "memory");
    if (tt < 31) STAGE((tt + 1) & 1, mbase + (tt + 1) * 32)

    const char* kbuf = (const char*)kls[tt & 1];
    const char* vbuf = (const char*)vls[tt & 1];

    // ---- St = K . Q^T (32m x 32n) -----------------------------------------
    f32x16 st;
#pragma unroll
    for (int e = 0; e < 16; ++e) st[e] = 0.f;
    __builtin_amdgcn_s_setprio(1);
#pragma unroll
    for (int kc = 0; kc < 8; ++kc) {
      short8 kf = *(const short8*)(kbuf + c32 * 256 +
                                   ((kc * 32 + hl * 16) ^ ((c32 & 7) << 4)));
      st = __builtin_amdgcn_mfma_f32_32x32x16_bf16(kf, q[kc], st, 0, 0, 0);
    }
    __builtin_amdgcn_s_setprio(0);

    // ---- online softmax over m (base-2; col n = lane&31) ------------------
    float sm = st[0];
#pragma unroll
    for (int e = 1; e < 16; ++e) sm = fmaxf(sm, st[e]);
    sm = fmaxf(sm, __shfl_xor(sm, 32));
    if (!__all(sm <= M + 11.5f)) {          // defer-max (T13, 8 nats)
      float Mn = fmaxf(M, sm);
      float scl = exp2_f(M - Mn);
      M = Mn;
      L *= scl;
#pragma unroll
      for (int it = 0; it < 4; ++it)
#pragma unroll
        for (int e = 0; e < 16; ++e) o[it][e] *= scl;
    }
    float pr[16];
#pragma unroll
    for (int e = 0; e < 16; ++e) pr[e] = exp2_f(st[e] - M);
    float ls = 0.f;
#pragma unroll
    for (int e = 0; e < 16; ++e) ls += pr[e];
    ls += __shfl_xor(ls, 32);
    L += ls;

    // ---- P^T -> B-fragments (2 x k16), cvt_pk + lane^32 bpermute ----------
    short8 pf[2];
#pragma unroll
    for (int kt = 0; kt < 2; ++kt) {
      unsigned a0 = cvt_pk(pr[kt * 8 + 0], pr[kt * 8 + 1]);
      unsigned a1 = cvt_pk(pr[kt * 8 + 2], pr[kt * 8 + 3]);
      unsigned a2 = cvt_pk(pr[kt * 8 + 4], pr[kt * 8 + 5]);
      unsigned a3 = cvt_pk(pr[kt * 8 + 6], pr[kt * 8 + 7]);
      unsigned x0 = (unsigned)__builtin_amdgcn_ds_bpermute(idxswap, (int)a0);
      unsigned x1 = (unsigned)__builtin_amdgcn_ds_bpermute(idxswap, (int)a1);
      unsigned x2 = (unsigned)__builtin_amdgcn_ds_bpermute(idxswap, (int)a2);
      unsigned x3 = (unsigned)__builtin_amdgcn_ds_bpermute(idxswap, (int)a3);
      union { unsigned u[4]; short8 s; } w;
      w.u[0] = hl ? x2 : a0;
      w.u[1] = hl ? x3 : a1;
      w.u[2] = hl ? a2 : x0;
      w.u[3] = hl ? a3 : x1;
      pf[kt] = w.s;
    }

    // ---- Ot += Vt . P^T ---------------------------------------------------
    __builtin_amdgcn_s_setprio(1);
#pragma unroll
    for (int it = 0; it < 4; ++it) {
#pragma unroll
      for (int kt = 0; kt < 2; ++kt) {
        int row = it * 32 + c32;
        short8 vf = *(const short8*)(vbuf + row * 64 +
                                     ((kt * 32 + hl * 16) ^ ((row & 3) << 4)));
        o[it] = __builtin_amdgcn_mfma_f32_32x32x16_bf16(vf, pf[kt], o[it], 0, 0, 0);
      }
    }
    __builtin_amdgcn_s_setprio(0);
  }
#undef STAGE

  // ---- store unnormalized partial O (fragment-order) + (M,L) --------------
  // Op[(ms*4+b)][cblk=i>>3][n][e]; lane covers i = it*32+8*g2+4*hl+0..3
  {
    const int sb = ms * 4 + b;
    unsigned short* Ob = Op + (size_t)sb * (16 * NTOK * 8);
#pragma unroll
    for (int it = 0; it < 4; ++it)
#pragma unroll
      for (int g2 = 0; g2 < 4; ++g2) {
        uint2 u2 = make_uint2(cvt_pk(o[it][4 * g2 + 0], o[it][4 * g2 + 1]),
                              cvt_pk(o[it][4 * g2 + 2], o[it][4 * g2 + 3]));
        *(uint2*)&Ob[((size_t)(it * 4 + g2) * NTOK + n0 + c32) * 8 + 4 * hl] = u2;
      }
    if (hl == 0) ML[(size_t)sb * NTOK + n0 + c32] = make_float2(M, L);
  }
}

// ---------------------------------------------------------------------------
// Phase 3: fused 4-split combine + out proj + residual, MFMA.
// out[b][c][n] = x[b][c][n] + sum_i wo[c][i] * (combined O)[n][i]
// ---------------------------------------------------------------------------
__global__ __launch_bounds__(256) void out_kernel(
    const float* __restrict__ x, const unsigned short* __restrict__ Wb,
    const unsigned short* __restrict__ Op, const float2* __restrict__ ML,
    float* __restrict__ out)
{
  const int b = blockIdx.y;
  const int n0 = blockIdx.x * 32;
  const int t = threadIdx.x;
  const int lane = t & 63;
  const int wv = __builtin_amdgcn_readfirstlane(t >> 6);
  const int cl = lane & 15, g = lane >> 4;

  // per-nsb combine weights (pre-multiplied by 1/Lx)
  float ws4[2][4];
#pragma unroll
  for (int nsb = 0; nsb < 2; ++nsb) {
    int n = n0 + nsb * 16 + cl;
    float2 m0 = ML[(size_t)(0 * 4 + b) * NTOK + n];
    float2 m1 = ML[(size_t)(1 * 4 + b) * NTOK + n];
    float2 m2 = ML[(size_t)(2 * 4 + b) * NTOK + n];
    float2 m3 = ML[(size_t)(3 * 4 + b) * NTOK + n];
    float Mx = fmaxf(fmaxf(m0.x, m1.x), fmaxf(m2.x, m3.x));
    float w0 = exp2_f(m0.x - Mx), w1 = exp2_f(m1.x - Mx);
    float w2 = exp2_f(m2.x - Mx), w3 = exp2_f(m3.x - Mx);
    float rinv = 1.f / (w0 * m0.y + w1 * m1.y + w2 * m2.y + w3 * m3.y);
    ws4[nsb][0] = w0 * rinv; ws4[nsb][1] = w1 * rinv;
    ws4[nsb][2] = w2 * rinv; ws4[nsb][3] = w3 * rinv;
  }

  f32x4 acc[4][2];
#pragma unroll
  for (int cs = 0; cs < 4; ++cs)
#pragma unroll
    for (int nsb = 0; nsb < 2; ++nsb) acc[cs][nsb] = (f32x4){0.f, 0.f, 0.f, 0.f};

#pragma unroll
  for (int kc = 0; kc < 4; ++kc) {
    short8 bf[2];
#pragma unroll
    for (int nsb = 0; nsb < 2; ++nsb) {
      int n = n0 + nsb * 16 + cl;
      size_t base = ((size_t)(kc * 4 + g) * NTOK + n) * 8;
      const short8 f0 = *(const short8*)&Op[(size_t)(0 * 4 + b) * (16 * NTOK * 8) + base];
      const short8 f1 = *(const short8*)&Op[(size_t)(1 * 4 + b) * (16 * NTOK * 8) + base];
      const short8 f2 = *(const short8*)&Op[(size_t)(2 * 4 + b) * (16 * NTOK * 8) + base];
      const short8 f3 = *(const short8*)&Op[(size_t)(3 * 4 + b) * (16 * NTOK * 8) + base];
      float a[8];
#pragma unroll
      for (int e = 0; e < 8; ++e)
        a[e] = ws4[nsb][0] * bf2f((unsigned short)f0[e]) +
               ws4[nsb][1] * bf2f((unsigned short)f1[e]) +
               ws4[nsb][2] * bf2f((unsigned short)f2[e]) +
               ws4[nsb][3] * bf2f((unsigned short)f3[e]);
      union { unsigned u[4]; short8 s; } r;
#pragma unroll
      for (int jp = 0; jp < 4; ++jp) r.u[jp] = cvt_pk(a[2 * jp], a[2 * jp + 1]);
      bf[nsb] = r.s;
    }
#pragma unroll
    for (int cs = 0; cs < 4; ++cs) {
      short8 af = *(const short8*)&Wb[98304 +
          (((size_t)(kc * 4 + g)) * 256 + wv * 64 + cs * 16 + cl) * 8];
#pragma unroll
      for (int nsb = 0; nsb < 2; ++nsb)
        acc[cs][nsb] = __builtin_amdgcn_mfma_f32_16x16x32_bf16(af, bf[nsb], acc[cs][nsb], 0, 0, 0);
    }
  }

  const float* xb = x + (size_t)b * CDIM * NTOK;
  float* ob = out + (size_t)b * CDIM * NTOK;
#pragma unroll
  for (int cs = 0; cs < 4; ++cs)
#pragma unroll
    for (int nsb = 0; nsb < 2; ++nsb)
#pragma unroll
      for (int r = 0; r < 4; ++r) {
        int c = wv * 64 + cs * 16 + g * 4 + r;
        int n = n0 + nsb * 16 + cl;
        ob[(size_t)c * NTOK + n] = xb[(size_t)c * NTOK + n] + acc[cs][nsb][r];
      }
}

extern "C" void kernel_launch(void* const* d_in, const int* in_sizes, int n_in,
                              void* d_out, int out_size, void* d_ws, size_t ws_size,
                              hipStream_t stream) {
  const float* x  = (const float*)d_in[0];
  const float* wt = (const float*)d_in[1];
  const float* wp = (const float*)d_in[2];
  const float* wg = (const float*)d_in[3];
  const float* wo = (const float*)d_in[4];
  float* outp = (float*)d_out;

  char* ws = (char*)d_ws;
  unsigned short* Wb  = (unsigned short*)(ws);                          // 256KB
  unsigned short* Qd  = (unsigned short*)(ws + (size_t)1  * (1 << 20)); // 4MB
  unsigned short* Kd  = (unsigned short*)(ws + (size_t)5  * (1 << 20)); // 4MB
  unsigned short* Vtd = (unsigned short*)(ws + (size_t)9  * (1 << 20)); // 4MB
  unsigned short* Opd = (unsigned short*)(ws + (size_t)13 * (1 << 20)); // 16MB
  float2* MLd         = (float2*)(ws + (size_t)29 * (1 << 20));         // 512KB

  cast_w_kernel<<<128, 256, 0, stream>>>(wt, wp, wg, wo, Wb);
  qkv_kernel<<<dim3(64, BATCH), 768, 0, stream>>>(x, Wb, Qd, Kd, Vtd);
  attn_kernel<<<1024, 128, 0, stream>>>(Qd, Kd, Vtd, Opd, MLd);
  out_kernel<<<dim3(128, BATCH), 256, 0, stream>>>(x, Wb, Opd, MLd, outp);
}

// Round 5
// 80.915 us; speedup vs baseline: 5.9356x; 1.0755x over previous
//
#include <hip/hip_runtime.h>
#include <hip/hip_bf16.h>
#include <cstdint>

#define BATCH 4
#define CDIM 256
#define NTOK 4096
#define IDIM 128

typedef __attribute__((ext_vector_type(4))) float f32x4;
typedef __attribute__((ext_vector_type(16))) float f32x16;
typedef __attribute__((ext_vector_type(8))) short short8;

static __device__ __forceinline__ unsigned cvt_pk(float lo, float hi) {
  unsigned r;
  asm("v_cvt_pk_bf16_f32 %0, %1, %2" : "=v"(r) : "v"(lo), "v"(hi));
  return r;
}
static __device__ __forceinline__ float bf2f(unsigned short u) {
  union { unsigned u; float f; } v;
  v.u = (unsigned)u << 16;
  return v.f;
}
static __device__ __forceinline__ float exp2_f(float x) {
#if __has_builtin(__builtin_amdgcn_exp2f)
  return __builtin_amdgcn_exp2f(x);
#else
  return exp2f(x);
#endif
}
// async global->LDS, 16B per lane. LDS dest = wave-uniform base + lane*16.
static __device__ __forceinline__ void gl16(const void* g, void* l) {
  __builtin_amdgcn_global_load_lds(
      (const __attribute__((address_space(1))) void*)g,
      (__attribute__((address_space(3))) void*)l, 16, 0, 0);
}

// ---------------------------------------------------------------------------
// Phase 0: cast weights fp32 -> bf16, into MFMA-fragment-order layouts.
//  proj p (theta/phi/g):  Wb[((p*32 + (c>>3))*128 + i)*8 + (c&7)] = w[i][c]
//    (theta additionally scaled by log2(e) -> softmax runs in base 2)
//  wo: Wb[98304 + ((i>>3)*256 + c)*8 + (i&7)] = wo[c][i]
// ---------------------------------------------------------------------------
__global__ __launch_bounds__(256) void cast_w_kernel(
    const float* __restrict__ wt, const float* __restrict__ wp,
    const float* __restrict__ wg, const float* __restrict__ wo,
    unsigned short* __restrict__ Wb)
{
  int id = blockIdx.x * 256 + threadIdx.x;   // 0..32767
  if (id < 24576) {
    int pidx = id >> 13;
    int rem = id & 8191;
    int i = rem >> 6, c4 = (rem & 63) * 4;
    const float* src = pidx == 0 ? wt : pidx == 1 ? wp : wg;
    float4 v = *(const float4*)&src[i * 256 + c4];
    float s = (pidx == 0) ? 1.4426950408889634f : 1.0f;
    uint2 u = make_uint2(cvt_pk(v.x * s, v.y * s), cvt_pk(v.z * s, v.w * s));
    *(uint2*)&Wb[(((size_t)pidx * 32 + (c4 >> 3)) * 128 + i) * 8 + (c4 & 7)] = u;
  } else {
    int rem = id - 24576;
    int c = rem >> 5, i4 = (rem & 31) * 4;
    float4 v = *(const float4*)&wo[c * 128 + i4];
    uint2 u = make_uint2(cvt_pk(v.x, v.y), cvt_pk(v.z, v.w));
    *(uint2*)&Wb[98304 + (((size_t)(i4 >> 3) * 256 + c) * 8) + (i4 & 7)] = u;
  }
}

// ---------------------------------------------------------------------------
// Phase 1: QKV projection, MFMA (unchanged from R4).
// ---------------------------------------------------------------------------
__global__ __launch_bounds__(768) void qkv_kernel(
    const float* __restrict__ x, const unsigned short* __restrict__ Wb,
    unsigned short* __restrict__ Q, unsigned short* __restrict__ K,
    unsigned short* __restrict__ Vt)
{
  __shared__ __align__(16) unsigned short xt[64 * 256];
  __shared__ __align__(16) unsigned short sc[8][16 * 128];

  const int b = blockIdx.y;
  const int n0 = blockIdx.x * 64;
  const int t = threadIdx.x;
  const float* xb = x + (size_t)b * CDIM * NTOK;

  for (int it = 0; it < 3; ++it) {
    int u = it * 768 + t;
    if (u < 2048) {
      int c0 = (u >> 4) * 2;
      int n4 = (u & 15) * 4;
      float4 va = *(const float4*)&xb[(size_t)c0 * NTOK + n0 + n4];
      float4 vb = *(const float4*)&xb[(size_t)(c0 + 1) * NTOK + n0 + n4];
      const float* pa = (const float*)&va;
      const float* pb = (const float*)&vb;
#pragma unroll
      for (int j = 0; j < 4; ++j) {
        int n = n4 + j;
        unsigned pk = cvt_pk(pa[j], pb[j]);
        *(unsigned*)((char*)xt + n * 512 + ((c0 * 2) ^ ((n & 15) << 4))) = pk;
      }
    }
  }
  __syncthreads();

  const int lane = t & 63;
  const int wv = __builtin_amdgcn_readfirstlane(t >> 6);
  const int nsub = wv & 3, proj = wv >> 2;
  const int cl = lane & 15, g = lane >> 4;

  f32x4 acc[8];
#pragma unroll
  for (int i = 0; i < 8; ++i) acc[i] = (f32x4){0.f, 0.f, 0.f, 0.f};

  const int nrow = nsub * 16 + cl;
  const int swz = (nrow & 15) << 4;
#pragma unroll
  for (int kc = 0; kc < 8; ++kc) {
    int cb = kc * 32 + g * 8;
    short8 af = *(const short8*)((const char*)xt + nrow * 512 + ((cb * 2) ^ swz));
#pragma unroll
    for (int is = 0; is < 8; ++is) {
      short8 bf = *(const short8*)&Wb[(((size_t)proj * 32 + kc * 4 + g) * 128 +
                                       is * 16 + cl) * 8];
      acc[is] = __builtin_amdgcn_mfma_f32_16x16x32_bf16(af, bf, acc[is], 0, 0, 0);
    }
  }

  if (proj < 2) {
    unsigned short* scw = sc[wv];
#pragma unroll
    for (int is = 0; is < 8; ++is)
#pragma unroll
      for (int r = 0; r < 4; ++r) {
        int nl = g * 4 + r;
        int i2 = (is * 16 + cl) * 2;
        *(unsigned short*)((char*)scw + nl * 256 + (i2 ^ ((nl & 15) << 4))) =
            (unsigned short)cvt_pk(acc[is][r], 0.f);
      }
    unsigned short* dst = (proj == 0 ? Q : K) +
        ((size_t)b * NTOK + n0 + nsub * 16) * IDIM;
    int nr = lane >> 2;
    int swr = (nr & 15) << 4;
#pragma unroll
    for (int j = 0; j < 4; ++j) {
      int ch = (lane & 3) + 4 * j;
      short8 v = *(const short8*)((const char*)scw + nr * 256 + ((ch * 16) ^ swr));
      *(short8*)&dst[(size_t)nr * IDIM + ch * 8] = v;
    }
  } else {
    unsigned short* dstV = Vt + (size_t)b * IDIM * NTOK + n0 + nsub * 16 + g * 4;
#pragma unroll
    for (int is = 0; is < 8; ++is) {
      uint2 u = make_uint2(cvt_pk(acc[is][0], acc[is][1]),
                           cvt_pk(acc[is][2], acc[is][3]));
      *(uint2*)&dstV[(size_t)(is * 16 + cl) * NTOK] = u;
    }
  }
}

// ---------------------------------------------------------------------------
// Phase 2: flash attention v5.
// vs v4: (a) V LDS layout -> row-pair 128B units, ppos = (rowbit*4+cc)^(rp&7)
//   => V ds_read_b128 spans all 8 bank-quartets (conflict-free minimum);
// (b) QK^T split into 2 independent 4-MFMA chains; (c) P-repack via
//   v_permlane32_swap_b32 (VALU) instead of 8 ds_bpermute; (d) all LDS read /
//   stage offsets hoisted to loop-invariant registers, staging uses
//   uniform-base + const-lane-offset addressing.
// ---------------------------------------------------------------------------
__global__ __launch_bounds__(128, 2) void attn_kernel(
    const unsigned short* __restrict__ Q, const unsigned short* __restrict__ K,
    const unsigned short* __restrict__ Vt, unsigned short* __restrict__ Op,
    float2* __restrict__ ML)
{
  __shared__ __align__(16) unsigned short kls[2][32 * 128];  // 16KB
  __shared__ __align__(16) unsigned short vls[2][128 * 32];  // 16KB

  const int bid = blockIdx.x;                  // bid&7 = XCD
  const int b = (bid >> 1) & 3;                // batch pinned to an XCD pair
  const int ms = (bid >> 3) & 3;               // m-split
  const int nblk = (bid >> 5) + (bid & 1) * 32;
  const int t = threadIdx.x;
  const int lane = t & 63;
  const int wv = __builtin_amdgcn_readfirstlane(t >> 6);
  const int n0 = nblk * 64 + wv * 32;
  const int c32 = lane & 31, hl = lane >> 5;
  const int p = t;                             // 0..127 staging id

  const unsigned short* Kb = K + (size_t)b * NTOK * IDIM;
  const unsigned short* Vb = Vt + (size_t)b * IDIM * NTOK;

  // Q fragments (B operand, 32x32x16): col=n (lane&31), k=i
  const unsigned short* Qp = Q + ((size_t)b * NTOK + n0 + c32) * IDIM + hl * 8;
  short8 q[8];
#pragma unroll
  for (int kc = 0; kc < 8; ++kc) q[kc] = *(const short8*)(Qp + kc * 16);

  // loop-invariant LDS byte offsets -----------------------------------------
  int koff[8];
#pragma unroll
  for (int kc = 0; kc < 8; ++kc)
    koff[kc] = c32 * 256 + ((((kc * 2 + hl) ^ (c32 & 7))) << 4);
  int voff[8];
#pragma unroll
  for (int it = 0; it < 4; ++it)
#pragma unroll
    for (int kt = 0; kt < 2; ++kt) {
      int rp = it * 16 + (c32 >> 1);
      voff[it * 2 + kt] =
          rp * 128 + ((((c32 & 1) * 4 + kt * 2 + hl) ^ (rp & 7)) << 4);
    }
  // loop-invariant staging offsets (element offsets into K/V, LDS byte offs)
  int kgo[4], vgo[4], lofs[4];
#pragma unroll
  for (int u = 0; u < 4; ++u) {
    int idx = p + 128 * u;
    lofs[u] = idx * 16;
    int r = idx >> 4, ch = idx & 15;
    kgo[u] = r * IDIM + ((ch ^ (r & 7)) * 8);
    int rp = idx >> 3, pp = idx & 7;
    int s = pp ^ (rp & 7);
    vgo[u] = (rp * 2 + (s >> 2)) * NTOK + (s & 3) * 8;
  }

  f32x16 o[4];
#pragma unroll
  for (int it = 0; it < 4; ++it)
#pragma unroll
    for (int e = 0; e < 16; ++e) o[it][e] = 0.f;
  float M = -3.0e38f, L = 0.f;

#define STAGE(cb, m0_)                                                        \
  {                                                                           \
    const unsigned short* Kit = Kb + (size_t)(m0_)*IDIM;                      \
    const unsigned short* Vit = Vb + (m0_);                                   \
    _Pragma("unroll")                                                         \
    for (int u = 0; u < 4; ++u)                                               \
      gl16(Kit + kgo[u], (char*)kls[cb] + lofs[u]);                           \
    _Pragma("unroll")                                                         \
    for (int u = 0; u < 4; ++u)                                               \
      gl16(Vit + vgo[u], (char*)vls[cb] + lofs[u]);                           \
  }

  const int mbase = ms * 1024;
  STAGE(0, mbase)

  for (int tt = 0; tt < 32; ++tt) {
    // own staged loads landed + own LDS reads drained, then join both waves.
    asm volatile("s_waitcnt vmcnt(0) lgkmcnt(0)\n\ts_barrier" ::: "memory");
    if (tt < 31) STAGE((tt + 1) & 1, mbase + (tt + 1) * 32)

    const char* kbuf = (const char*)kls[tt & 1];
    const char* vbuf = (const char*)vls[tt & 1];

    // ---- St = K . Q^T (32m x 32n), two independent 4-MFMA chains ----------
    f32x16 sa, sb;
#pragma unroll
    for (int e = 0; e < 16; ++e) { sa[e] = 0.f; sb[e] = 0.f; }
    __builtin_amdgcn_s_setprio(1);
#pragma unroll
    for (int kc = 0; kc < 4; ++kc) {
      short8 ka = *(const short8*)(kbuf + koff[kc]);
      short8 kb2 = *(const short8*)(kbuf + koff[kc + 4]);
      sa = __builtin_amdgcn_mfma_f32_32x32x16_bf16(ka, q[kc], sa, 0, 0, 0);
      sb = __builtin_amdgcn_mfma_f32_32x32x16_bf16(kb2, q[kc + 4], sb, 0, 0, 0);
    }
    __builtin_amdgcn_s_setprio(0);
    f32x16 st = sa + sb;

    // ---- online softmax over m (base-2; col n = lane&31), tree-reduced ----
    float mx[8];
#pragma unroll
    for (int j = 0; j < 8; ++j) mx[j] = fmaxf(st[j], st[j + 8]);
#pragma unroll
    for (int j = 0; j < 4; ++j) mx[j] = fmaxf(mx[j], mx[j + 4]);
    float sm = fmaxf(fmaxf(mx[0], mx[1]), fmaxf(mx[2], mx[3]));
    sm = fmaxf(sm, __shfl_xor(sm, 32));
    if (!__all(sm <= M + 11.5f)) {          // defer-max (T13, 8 nats)
      float Mn = fmaxf(M, sm);
      float scl = exp2_f(M - Mn);
      M = Mn;
      L *= scl;
#pragma unroll
      for (int it = 0; it < 4; ++it)
#pragma unroll
        for (int e = 0; e < 16; ++e) o[it][e] *= scl;
    }
    float pr[16];
#pragma unroll
    for (int e = 0; e < 16; ++e) pr[e] = exp2_f(st[e] - M);
    float sv[8];
#pragma unroll
    for (int j = 0; j < 8; ++j) sv[j] = pr[j] + pr[j + 8];
#pragma unroll
    for (int j = 0; j < 4; ++j) sv[j] += sv[j + 4];
    float ls = (sv[0] + sv[1]) + (sv[2] + sv[3]);
    ls += __shfl_xor(ls, 32);
    L += ls;

    // ---- P^T -> B-fragments: cvt_pk + v_permlane32_swap ------------------
    short8 pf[2];
#pragma unroll
    for (int kt = 0; kt < 2; ++kt) {
      unsigned a0 = cvt_pk(pr[kt * 8 + 0], pr[kt * 8 + 1]);
      unsigned a1 = cvt_pk(pr[kt * 8 + 2], pr[kt * 8 + 3]);
      unsigned a2 = cvt_pk(pr[kt * 8 + 4], pr[kt * 8 + 5]);
      unsigned a3 = cvt_pk(pr[kt * 8 + 6], pr[kt * 8 + 7]);
      // after swap: a0 = {a0_lo, a2_lo} (word0), a2 = {a0_hi, a2_hi} (word2)
      asm volatile("v_permlane32_swap_b32 %0, %1" : "+v"(a0), "+v"(a2));
      asm volatile("v_permlane32_swap_b32 %0, %1" : "+v"(a1), "+v"(a3));
      union { unsigned u[4]; short8 s; } w;
      w.u[0] = a0; w.u[1] = a1; w.u[2] = a2; w.u[3] = a3;
      pf[kt] = w.s;
    }

    // ---- Ot += Vt . P^T ---------------------------------------------------
    __builtin_amdgcn_s_setprio(1);
#pragma unroll
    for (int it = 0; it < 4; ++it) {
#pragma unroll
      for (int kt = 0; kt < 2; ++kt) {
        short8 vf = *(const short8*)(vbuf + voff[it * 2 + kt]);
        o[it] = __builtin_amdgcn_mfma_f32_32x32x16_bf16(vf, pf[kt], o[it], 0, 0, 0);
      }
    }
    __builtin_amdgcn_s_setprio(0);
  }
#undef STAGE

  // ---- store unnormalized partial O (fragment-order) + (M,L) --------------
  {
    const int sb2 = ms * 4 + b;
    unsigned short* Ob = Op + (size_t)sb2 * (16 * NTOK * 8);
#pragma unroll
    for (int it = 0; it < 4; ++it)
#pragma unroll
      for (int g2 = 0; g2 < 4; ++g2) {
        uint2 u2 = make_uint2(cvt_pk(o[it][4 * g2 + 0], o[it][4 * g2 + 1]),
                              cvt_pk(o[it][4 * g2 + 2], o[it][4 * g2 + 3]));
        *(uint2*)&Ob[((size_t)(it * 4 + g2) * NTOK + n0 + c32) * 8 + 4 * hl] = u2;
      }
    if (hl == 0) ML[(size_t)sb2 * NTOK + n0 + c32] = make_float2(M, L);
  }
}

// ---------------------------------------------------------------------------
// Phase 3: fused 4-split combine + out proj + residual, MFMA (unchanged).
// ---------------------------------------------------------------------------
__global__ __launch_bounds__(256) void out_kernel(
    const float* __restrict__ x, const unsigned short* __restrict__ Wb,
    const unsigned short* __restrict__ Op, const float2* __restrict__ ML,
    float* __restrict__ out)
{
  const int b = blockIdx.y;
  const int n0 = blockIdx.x * 32;
  const int t = threadIdx.x;
  const int lane = t & 63;
  const int wv = __builtin_amdgcn_readfirstlane(t >> 6);
  const int cl = lane & 15, g = lane >> 4;

  float ws4[2][4];
#pragma unroll
  for (int nsb = 0; nsb < 2; ++nsb) {
    int n = n0 + nsb * 16 + cl;
    float2 m0 = ML[(size_t)(0 * 4 + b) * NTOK + n];
    float2 m1 = ML[(size_t)(1 * 4 + b) * NTOK + n];
    float2 m2 = ML[(size_t)(2 * 4 + b) * NTOK + n];
    float2 m3 = ML[(size_t)(3 * 4 + b) * NTOK + n];
    float Mx = fmaxf(fmaxf(m0.x, m1.x), fmaxf(m2.x, m3.x));
    float w0 = exp2_f(m0.x - Mx), w1 = exp2_f(m1.x - Mx);
    float w2 = exp2_f(m2.x - Mx), w3 = exp2_f(m3.x - Mx);
    float rinv = 1.f / (w0 * m0.y + w1 * m1.y + w2 * m2.y + w3 * m3.y);
    ws4[nsb][0] = w0 * rinv; ws4[nsb][1] = w1 * rinv;
    ws4[nsb][2] = w2 * rinv; ws4[nsb][3] = w3 * rinv;
  }

  f32x4 acc[4][2];
#pragma unroll
  for (int cs = 0; cs < 4; ++cs)
#pragma unroll
    for (int nsb = 0; nsb < 2; ++nsb) acc[cs][nsb] = (f32x4){0.f, 0.f, 0.f, 0.f};

#pragma unroll
  for (int kc = 0; kc < 4; ++kc) {
    short8 bf[2];
#pragma unroll
    for (int nsb = 0; nsb < 2; ++nsb) {
      int n = n0 + nsb * 16 + cl;
      size_t base = ((size_t)(kc * 4 + g) * NTOK + n) * 8;
      const short8 f0 = *(const short8*)&Op[(size_t)(0 * 4 + b) * (16 * NTOK * 8) + base];
      const short8 f1 = *(const short8*)&Op[(size_t)(1 * 4 + b) * (16 * NTOK * 8) + base];
      const short8 f2 = *(const short8*)&Op[(size_t)(2 * 4 + b) * (16 * NTOK * 8) + base];
      const short8 f3 = *(const short8*)&Op[(size_t)(3 * 4 + b) * (16 * NTOK * 8) + base];
      float a[8];
#pragma unroll
      for (int e = 0; e < 8; ++e)
        a[e] = ws4[nsb][0] * bf2f((unsigned short)f0[e]) +
               ws4[nsb][1] * bf2f((unsigned short)f1[e]) +
               ws4[nsb][2] * bf2f((unsigned short)f2[e]) +
               ws4[nsb][3] * bf2f((unsigned short)f3[e]);
      union { unsigned u[4]; short8 s; } r;
#pragma unroll
      for (int jp = 0; jp < 4; ++jp) r.u[jp] = cvt_pk(a[2 * jp], a[2 * jp + 1]);
      bf[nsb] = r.s;
    }
#pragma unroll
    for (int cs = 0; cs < 4; ++cs) {
      short8 af = *(const short8*)&Wb[98304 +
          (((size_t)(kc * 4 + g)) * 256 + wv * 64 + cs * 16 + cl) * 8];
#pragma unroll
      for (int nsb = 0; nsb < 2; ++nsb)
        acc[cs][nsb] = __builtin_amdgcn_mfma_f32_16x16x32_bf16(af, bf[nsb], acc[cs][nsb], 0, 0, 0);
    }
  }

  const float* xb = x + (size_t)b * CDIM * NTOK;
  float* ob = out + (size_t)b * CDIM * NTOK;
#pragma unroll
  for (int cs = 0; cs < 4; ++cs)
#pragma unroll
    for (int nsb = 0; nsb < 2; ++nsb)
#pragma unroll
      for (int r = 0; r < 4; ++r) {
        int c = wv * 64 + cs * 16 + g * 4 + r;
        int n = n0 + nsb * 16 + cl;
        ob[(size_t)c * NTOK + n] = xb[(size_t)c * NTOK + n] + acc[cs][nsb][r];
      }
}

extern "C" void kernel_launch(void* const* d_in, const int* in_sizes, int n_in,
                              void* d_out, int out_size, void* d_ws, size_t ws_size,
                              hipStream_t stream) {
  const float* x  = (const float*)d_in[0];
  const float* wt = (const float*)d_in[1];
  const float* wp = (const float*)d_in[2];
  const float* wg = (const float*)d_in[3];
  const float* wo = (const float*)d_in[4];
  float* outp = (float*)d_out;

  char* ws = (char*)d_ws;
  unsigned short* Wb  = (unsigned short*)(ws);                          // 256KB
  unsigned short* Qd  = (unsigned short*)(ws + (size_t)1  * (1 << 20)); // 4MB
  unsigned short* Kd  = (unsigned short*)(ws + (size_t)5  * (1 << 20)); // 4MB
  unsigned short* Vtd = (unsigned short*)(ws + (size_t)9  * (1 << 20)); // 4MB
  unsigned short* Opd = (unsigned short*)(ws + (size_t)13 * (1 << 20)); // 16MB
  float2* MLd         = (float2*)(ws + (size_t)29 * (1 << 20));         // 512KB

  cast_w_kernel<<<128, 256, 0, stream>>>(wt, wp, wg, wo, Wb);
  qkv_kernel<<<dim3(64, BATCH), 768, 0, stream>>>(x, Wb, Qd, Kd, Vtd);
  attn_kernel<<<1024, 128, 0, stream>>>(Qd, Kd, Vtd, Opd, MLd);
  out_kernel<<<dim3(128, BATCH), 256, 0, stream>>>(x, Wb, Opd, MLd, outp);
}